// Round 6
// baseline (129.316 us; speedup 1.0000x reference)
//
#include <hip/hip_runtime.h>
#include <hip/hip_cooperative_groups.h>
#include <stdint.h>

namespace cg = cooperative_groups;

#define HH 96
#define WW 96
#define NN (HH*WW)
#define NW 192   // bitmap words: 96 rows x 2 (128-bit padded rows, cols 96..127 dead)

// ws layout (bytes):
//   [0,      331776)  rankp int32[9][9216]  (rank partial sums)
//   [331776, 333312)  kw    u64[192]        (kept bitmap words)

__device__ __forceinline__ int coord1(int a) { return (10 * a + 1) / 3; }

// Aligned shifted word: result bit b (cell col 64h+b) = src-row bit (64h+b+dj).
__device__ __forceinline__ unsigned long long shifted(unsigned long long A,
                                                      unsigned long long B,
                                                      int h, int dj) {
    const unsigned long long W0 = h ? B : A;
    if (dj == 0) return W0;
    if (dj > 0) {
        const unsigned long long Wr = h ? 0ULL : B;
        return (W0 >> dj) | (Wr << (64 - dj));
    }
    const int d = -dj;
    const unsigned long long Wl = h ? A : 0ULL;
    return (W0 << d) | (Wl >> (64 - d));
}

// Single cooperative dispatch (R5 post-mortem: dur = ~79us harness ws-poison
// floor + ~38us of ours across 3 serial dispatches; krank and knms are
// independent, so run them on disjoint blocks and grid.sync once).
// Block 0: R5's bit-parallel greedy-NMS fixpoint (== lexicographically-first
// MIS; exact-integer iou>0.5 test per R0 analysis; 2nd NMS pass @0.7 provably
// a no-op). Blocks 1..81: counting-rank partials. After sync: epilogue.
__global__ __launch_bounds__(1024, 1) void kfused(const float* __restrict__ cls,
                                                  const float* __restrict__ reg,
                                                  int* __restrict__ rankp,
                                                  unsigned long long* __restrict__ kw,
                                                  float* __restrict__ out) {
    __shared__ float s[NN];                       // 36 KB (rank blocks alias 4 KB)
    __shared__ unsigned long long Hh[12][NW];     // 18 KB
    __shared__ unsigned long long K[NW], D[NW];   // 3 KB
    const int tid = threadIdx.x;
    const int bid = blockIdx.x;

    if (bid == 0) {
        // ---- NMS fixpoint (validated R5 logic) ----
        const int lane = tid & 63;
        const int wave = tid >> 6;
        const int offs_di[12] = {0,0, 0,0, -1,1, -2,2, -1,-1, 1,1};
        const int offs_dj[12] = {-1,1,-2,2,  0,0,  0,0, -1, 1,-1,1};
        for (int i = tid; i < NN/4; i += 1024)
            ((float4*)s)[i] = ((const float4*)cls)[i];
        __syncthreads();
        // Build H masks + K/D init via ballot. Word w: row w>>1, col base
        // 64*(w&1); lane l <-> col base+l. 16 waves x 12 iters = 192 words.
        for (int it = 0; it < 12; ++it) {
            const int w = wave + (it << 4);
            const int row = w >> 1;
            const int col = ((w & 1) << 6) + lane;
            const bool incell = (col < WW);
            const int c = row * WW + col;
            const float sc = incell ? s[c] : 0.0f;
            const int xi = coord1(col), yi = coord1(row);
            const unsigned long long dinit = __ballot(!incell || !(sc > 0.6f));
            if (lane == 0) { D[w] = dinit; K[w] = 0ULL; }
            #pragma unroll
            for (int e = 0; e < 12; ++e) {
                const int ii = row + offs_di[e], jj = col + offs_dj[e];
                bool hp = false;
                if (incell && ii >= 0 && ii < HH && jj >= 0 && jj < WW) {
                    int dx = xi - coord1(jj); dx = dx < 0 ? -dx : dx;
                    int dy = yi - coord1(ii); dy = dy < 0 ? -dy : dy;
                    if ((21 - dx) * (21 - dy) > 294) {   // exact iou>0.5
                        const int v = ii * WW + jj;
                        const float sv = s[v];
                        hp = (sv > sc) || (sv == sc && v < c);
                    }
                }
                const unsigned long long m = __ballot(hp);
                if (lane == 0) Hh[e][w] = m;
            }
        }
        __syncthreads();
        // Fixpoint: thread w<192 owns word w. Stale/torn reads safe (monotone).
        unsigned long long Hr[12];
        const int w = tid;
        int row = 0, h = 0;
        if (w < NW) {
            #pragma unroll
            for (int e = 0; e < 12; ++e) Hr[e] = Hh[e][w];
            row = w >> 1; h = w & 1;
        }
        for (int round = 0; round < 256; ++round) {
            int undet = 0;
            if (w < NW) {
                const unsigned long long Dw = D[w];
                if (~Dw) {
                    unsigned long long KA[5], KB[5], DA[5], DB[5];
                    #pragma unroll
                    for (int q = 0; q < 5; ++q) {
                        const int rr = row + q - 2;
                        const bool ok = (rr >= 0) && (rr < HH);
                        KA[q] = ok ? K[rr*2]   : 0ULL;
                        KB[q] = ok ? K[rr*2+1] : 0ULL;
                        DA[q] = ok ? D[rr*2]   : 0ULL;
                        DB[q] = ok ? D[rr*2+1] : 0ULL;
                    }
                    unsigned long long supp = 0ULL, alldet = ~0ULL;
                    const int offs_di2[12] = {0,0, 0,0, -1,1, -2,2, -1,-1, 1,1};
                    const int offs_dj2[12] = {-1,1,-2,2,  0,0,  0,0, -1, 1,-1,1};
                    #pragma unroll
                    for (int e = 0; e < 12; ++e) {
                        const int q = offs_di2[e] + 2;
                        const int dj = offs_dj2[e];
                        supp   |=  Hr[e] & shifted(KA[q], KB[q], h, dj);
                        alldet &= ~Hr[e] | shifted(DA[q], DB[q], h, dj);
                    }
                    const unsigned long long U = ~Dw;
                    const unsigned long long newK = K[w] | (U & alldet & ~supp);
                    const unsigned long long newD = Dw | (U & (supp | alldet));
                    K[w] = newK; D[w] = newD;
                    undet = ((~newD) != 0ULL) ? 1 : 0;
                }
            }
            if (__syncthreads_count(undet) == 0) break;
        }
        if (w < NW) kw[w] = K[w];
    } else {
        // ---- counting-rank partials: pair p = (k-tile, m-tile), 1024 each ----
        float4* smf = (float4*)s;   // alias: 4 KB of the NMS score buffer
        for (int p = bid - 1; p < 81; p += 255) {
            const int kt = p % 9, mt = p / 9;
            const int base = mt * 1024;
            __syncthreads();        // protect LDS reuse across p-iterations
            if (tid < 256) smf[tid] = ((const float4*)(cls + base))[tid];
            __syncthreads();
            const int k = kt * 1024 + tid;
            const float sk = cls[k];
            int cnt = 0;
            #pragma unroll 4
            for (int m4 = 0; m4 < 256; ++m4) {
                const float4 v = smf[m4];
                const int gm = base + (m4 << 2);
                cnt += (v.x > sk) || (v.x == sk && (gm + 0) < k);
                cnt += (v.y > sk) || (v.y == sk && (gm + 1) < k);
                cnt += (v.z > sk) || (v.z == sk && (gm + 2) < k);
                cnt += (v.w > sk) || (v.w == sk && (gm + 3) < k);
            }
            rankp[mt * NN + k] = cnt;
        }
    }

    cg::this_grid().sync();

    // ---- epilogue: r = rank[k] is a permutation of [0,9216), every output
    // row written exactly once (non-kept rows -> zeros, no d_out memset) ----
    const int k = bid * 1024 + tid;
    if (k < NN) {
        int r = 0;
        #pragma unroll
        for (int y = 0; y < 9; ++y) r += rankp[y * NN + k];
        const int j = k % WW, i = k / WW;
        const bool kp = ((kw[i * 2 + (j >> 6)] >> (j & 63)) & 1ULL) != 0ULL;
        const float x1 = (float)coord1(j);
        const float y1 = (float)coord1(i);
        const float d0 = reg[k * 4 + 0];
        const float d1 = reg[k * 4 + 1];
        const float d2 = reg[k * 4 + 2];
        const float d3 = reg[k * 4 + 3];
        float* o = out + (size_t)r * 5;
        o[0] = kp ? (x1 + d0 * 21.0f) : 0.0f;
        o[1] = kp ? (y1 + d1 * 21.0f) : 0.0f;
        o[2] = kp ? (x1 + 20.0f + d2 * 21.0f) : 0.0f;
        o[3] = kp ? (y1 + 20.0f + d3 * 21.0f) : 0.0f;
        o[4] = kp ? cls[k] : 0.0f;
    }
}

extern "C" void kernel_launch(void* const* d_in, const int* in_sizes, int n_in,
                              void* d_out, int out_size, void* d_ws, size_t ws_size,
                              hipStream_t stream) {
    const float* cls = (const float*)d_in[0];
    const float* reg = (const float*)d_in[1];
    float* out = (float*)d_out;
    char* ws = (char*)d_ws;
    int* rankp = (int*)(ws);
    unsigned long long* kw = (unsigned long long*)(ws + 331776);

    void* args[] = { (void*)&cls, (void*)&reg, (void*)&rankp, (void*)&kw, (void*)&out };
    hipLaunchCooperativeKernel((void*)kfused, dim3(256), dim3(1024), args, 0, stream);
}

// Round 8
// 124.611 us; speedup vs baseline: 1.0378x; 1.0378x over previous
//
#include <hip/hip_runtime.h>
#include <stdint.h>

#define HH 96
#define WW 96
#define NN (HH*WW)
#define NW 192   // bitmap words: 96 rows x 2 (128-bit padded rows, cols 96..127 dead)

// ws layout (bytes):
//   [0,      331776)  rankp int32[9][9216]   rank partial sums
//   [331776, 333312)  kw    u64[192]         kept bitmap
//   [333312, 351744)  Hg    u64[12][192]     edge masks (higher-prio overlap)
//   [351744, 351756)  flags int32[3]         {h_done, rank_done, nms_done} (memset 0)

__device__ __forceinline__ int coord1(int a) { return (10 * a + 1) / 3; }

// Aligned shifted word: result bit b (cell col 64h+b) = src-row bit (64h+b+dj).
__device__ __forceinline__ unsigned long long shifted(unsigned long long A,
                                                      unsigned long long B,
                                                      int h, int dj) {
    const unsigned long long W0 = h ? B : A;
    if (dj == 0) return W0;
    if (dj > 0) {
        const unsigned long long Wr = h ? 0ULL : B;
        return (W0 >> dj) | (Wr << (64 - dj));
    }
    const int d = -dj;
    const unsigned long long Wl = h ? A : 0ULL;
    return (W0 << d) | (Wl >> (64 - d));
}

__device__ __forceinline__ void release_and_bump(int* flag) {
    // all threads: flush own stores (device scope); then one thread publishes
    __syncthreads();
    __threadfence();
    if (threadIdx.x == 0)
        __hip_atomic_fetch_add(flag, 1, __ATOMIC_RELEASE, __HIP_MEMORY_SCOPE_AGENT);
}

__device__ __forceinline__ void spin_until(int* flag, int target) {
    if (threadIdx.x == 0) {
        while (__hip_atomic_load(flag, __ATOMIC_ACQUIRE, __HIP_MEMORY_SCOPE_AGENT) < target)
            __builtin_amdgcn_s_sleep(2);
    }
    __syncthreads();
    __threadfence();
}

// Single launch, role-specialized blocks (103 blocks <= 256 CUs: all resident,
// spin-waits deadlock-free). R6 post-mortem: grid.sync serialized everything
// behind the NMS block and the 14us H-build sat on ONE CU; here H builds on 12
// blocks in parallel with the master's staging, and only consumers spin.
__global__ __launch_bounds__(1024) void kmain(const float* __restrict__ cls,
                                              const float* __restrict__ reg,
                                              int* __restrict__ rankp,
                                              unsigned long long* __restrict__ kw,
                                              unsigned long long* __restrict__ Hg,
                                              int* __restrict__ flags,
                                              float* __restrict__ out) {
    __shared__ __align__(16) float s[NN];          // 36 KB
    __shared__ ulonglong2 K2[HH], D2[HH];          // 3 KB (row-indexed halves)
    const int tid = threadIdx.x;
    const int bid = blockIdx.x;
    const int lane = tid & 63;
    const int wave = tid >> 6;
    int* h_done   = flags + 0;
    int* rank_done = flags + 1;
    int* nms_done = flags + 2;
    const int offs_di[12] = {0,0, 0,0, -1,1, -2,2, -1,-1, 1,1};
    const int offs_dj[12] = {-1,1,-2,2,  0,0,  0,0, -1, 1,-1,1};

    if (bid == 0) {
        // ---- master: stage scores, init K/D, then fixpoint on H ----
        unsigned long long* Kw = (unsigned long long*)K2;   // word-indexed
        unsigned long long* Dw = (unsigned long long*)D2;
        for (int i = tid; i < NN/4; i += 1024)
            ((float4*)s)[i] = ((const float4*)cls)[i];
        __syncthreads();
        // K=0; D bit set iff invalid (col>=96 or score<=0.6): ballot per word
        for (int it = 0; it < 12; ++it) {
            const int w = wave + (it << 4);
            const int row = w >> 1;
            const int col = ((w & 1) << 6) + lane;
            const bool incell = (col < WW);
            const float sc = incell ? s[row * WW + col] : 0.0f;
            const unsigned long long dinit = __ballot(!incell || !(sc > 0.6f));
            if (lane == 0) { Dw[w] = dinit; Kw[w] = 0ULL; }
        }
        __syncthreads();
        spin_until(h_done, 12);
        // per-thread H row (from global; LLC-resident, 12 coalesced u64 loads)
        unsigned long long Hr[12];
        const int w = tid;
        int row = 0, h = 0;
        if (w < NW) {
            #pragma unroll
            for (int e = 0; e < 12; ++e) Hr[e] = Hg[e * NW + w];
            row = w >> 1; h = w & 1;
        }
        // monotone fixpoint (R5-validated logic): KEPT when all higher-prio
        // overlapping neighbors determined & none kept; SUPP when one kept.
        for (int round = 0; round < 256; ++round) {
            int undet = 0;
            if (w < NW) {
                const unsigned long long Dme = Dw[w];
                if (~Dme) {
                    ulonglong2 kk[5], dd[5];
                    #pragma unroll
                    for (int q = 0; q < 5; ++q) {
                        const int rr = row + q - 2;
                        const bool ok = (rr >= 0) && (rr < HH);
                        kk[q] = ok ? K2[rr] : (ulonglong2){0ULL, 0ULL};
                        dd[q] = ok ? D2[rr] : (ulonglong2){0ULL, 0ULL};  // H=0 there
                    }
                    unsigned long long supp = 0ULL, alldet = ~0ULL;
                    #pragma unroll
                    for (int e = 0; e < 12; ++e) {
                        const int q = offs_di[e] + 2;
                        const int dj = offs_dj[e];
                        supp   |=  Hr[e] & shifted(kk[q].x, kk[q].y, h, dj);
                        alldet &= ~Hr[e] | shifted(dd[q].x, dd[q].y, h, dj);
                    }
                    const unsigned long long U = ~Dme;
                    const unsigned long long newK = Kw[w] | (U & alldet & ~supp);
                    const unsigned long long newD = Dme | (U & (supp | alldet));
                    Kw[w] = newK; Dw[w] = newD;
                    undet = ((~newD) != 0ULL) ? 1 : 0;
                }
            }
            if (__syncthreads_count(undet) == 0) break;
        }
        if (w < NW) kw[w] = Kw[w];
        release_and_bump(nms_done);
    } else if (bid <= 12) {
        // ---- H-build: one edge per block, 192 ballot words ----
        const int e = bid - 1;
        const int di = offs_di[e], dj = offs_dj[e];
        for (int i = tid; i < NN/4; i += 1024)
            ((float4*)s)[i] = ((const float4*)cls)[i];
        __syncthreads();
        for (int it = 0; it < 12; ++it) {
            const int w = wave + (it << 4);
            const int row = w >> 1;
            const int col = ((w & 1) << 6) + lane;
            const bool incell = (col < WW);
            const int c = row * WW + col;
            bool hp = false;
            const int ii = row + di, jj = col + dj;
            if (incell && ii >= 0 && ii < HH && jj >= 0 && jj < WW) {
                int dx = coord1(col) - coord1(jj); dx = dx < 0 ? -dx : dx;
                int dy = coord1(row) - coord1(ii); dy = dy < 0 ? -dy : dy;
                if ((21 - dx) * (21 - dy) > 294) {   // exact iou>0.5 (R0 analysis)
                    const float sc = s[c];
                    const int v = ii * WW + jj;
                    const float sv = s[v];
                    hp = (sv > sc) || (sv == sc && v < c);
                }
            }
            const unsigned long long m = __ballot(hp);
            if (lane == 0) Hg[e * NW + w] = m;
        }
        release_and_bump(h_done);
    } else if (bid <= 93) {
        // ---- rank partials: pair p=(k-tile, m-tile) of 1024 cells each ----
        const int p = bid - 13;
        const int kt = p % 9, mt = p / 9;
        const int base = mt * 1024;
        float4* smf = (float4*)s;
        if (tid < 256) smf[tid] = ((const float4*)(cls + base))[tid];
        __syncthreads();
        const int k = kt * 1024 + tid;
        const float sk = cls[k];
        int cnt = 0;
        #pragma unroll 4
        for (int m4 = 0; m4 < 256; ++m4) {
            const float4 v = smf[m4];
            const int gm = base + (m4 << 2);
            cnt += (v.x > sk) || (v.x == sk && (gm + 0) < k);
            cnt += (v.y > sk) || (v.y == sk && (gm + 1) < k);
            cnt += (v.z > sk) || (v.z == sk && (gm + 2) < k);
            cnt += (v.w > sk) || (v.w == sk && (gm + 3) < k);
        }
        rankp[mt * NN + k] = cnt;
        release_and_bump(rank_done);
    } else {
        // ---- out: r = rank[k] is a permutation of [0,9216); every row
        // written exactly once (non-kept -> zeros, no d_out memset) ----
        spin_until(rank_done, 81);
        spin_until(nms_done, 1);
        const int k = (bid - 94) * 1024 + tid;
        int r = 0;
        #pragma unroll
        for (int y = 0; y < 9; ++y) r += rankp[y * NN + k];
        const int j = k % WW, i = k / WW;
        const bool kp = ((kw[i * 2 + (j >> 6)] >> (j & 63)) & 1ULL) != 0ULL;
        const float x1 = (float)coord1(j);
        const float y1 = (float)coord1(i);
        const float4 d = ((const float4*)reg)[k];
        float* o = out + (size_t)r * 5;
        o[0] = kp ? (x1 + d.x * 21.0f) : 0.0f;
        o[1] = kp ? (y1 + d.y * 21.0f) : 0.0f;
        o[2] = kp ? (x1 + 20.0f + d.z * 21.0f) : 0.0f;
        o[3] = kp ? (y1 + 20.0f + d.w * 21.0f) : 0.0f;
        o[4] = kp ? cls[k] : 0.0f;
    }
}

extern "C" void kernel_launch(void* const* d_in, const int* in_sizes, int n_in,
                              void* d_out, int out_size, void* d_ws, size_t ws_size,
                              hipStream_t stream) {
    const float* cls = (const float*)d_in[0];
    const float* reg = (const float*)d_in[1];
    float* out = (float*)d_out;
    char* ws = (char*)d_ws;
    int* rankp = (int*)(ws);
    unsigned long long* kw = (unsigned long long*)(ws + 331776);
    unsigned long long* Hg = (unsigned long long*)(ws + 333312);
    int* flags = (int*)(ws + 351744);

    (void)hipMemsetAsync(flags, 0, 12, stream);  // ws is 0xAA-poisoned; flags must start 0
    kmain<<<103, 1024, 0, stream>>>(cls, reg, rankp, kw, Hg, flags, out);
}

// Round 9
// 97.881 us; speedup vs baseline: 1.3212x; 1.2731x over previous
//
#include <hip/hip_runtime.h>
#include <stdint.h>

#define HH 96
#define WW 96
#define NN (HH*WW)
#define NW 192   // bitmap words: 96 rows x 2 (128-bit padded rows, cols 96..127 dead)

// ws layout (bytes):
//   [0,      331776)  rankp int32[9][9216]  (rank partial sums)
//   [331776, 333312)  kw    u64[192]        (kept bitmap words)

__device__ __forceinline__ int coord1(int a) { return (10 * a + 1) / 3; }

// Aligned shifted word: result bit b (cell col 64h+b) = src-row bit (64h+b+dj).
__device__ __forceinline__ unsigned long long shifted(unsigned long long A,
                                                      unsigned long long B,
                                                      int h, int dj) {
    const unsigned long long W0 = h ? B : A;
    if (dj == 0) return W0;
    if (dj > 0) {
        const unsigned long long Wr = h ? 0ULL : B;
        return (W0 >> dj) | (Wr << (64 - dj));
    }
    const int d = -dj;
    const unsigned long long Wl = h ? A : 0ULL;
    return (W0 << d) | (Wl >> (64 - d));
}

// One dispatch, disjoint block roles, ZERO cross-block sync (R6/R8 post-mortem:
// grid.sync and flag-spins both cost more than the dispatch gap they save).
// Blocks 0..80: counting-rank partials. Block 81: R5's validated bit-parallel
// greedy-NMS fixpoint (== lexicographically-first MIS; exact-integer iou>0.5
// per R0 analysis; the 2nd NMS pass @0.7 is provably a no-op).
__global__ __launch_bounds__(1024, 1) void kA(const float* __restrict__ cls,
                                              int* __restrict__ rankp,
                                              unsigned long long* __restrict__ kw) {
    __shared__ __align__(16) float s[NN];         // 36 KB (rank blocks use 4 KB)
    __shared__ unsigned long long Hh[12][NW];     // 18 KB
    __shared__ unsigned long long K[NW], D[NW];   // 3 KB
    const int tid = threadIdx.x;
    const int bid = blockIdx.x;

    if (bid < 81) {
        // ---- rank partials: pair p=(k-tile, m-tile) of 1024 cells each ----
        const int kt = bid % 9, mt = bid / 9;
        const int base = mt * 1024;
        float4* smf = (float4*)s;
        if (tid < 256) smf[tid] = ((const float4*)(cls + base))[tid];
        __syncthreads();
        const int k = kt * 1024 + tid;
        const float sk = cls[k];
        int cnt = 0;
        #pragma unroll 4
        for (int m4 = 0; m4 < 256; ++m4) {
            const float4 v = smf[m4];
            const int gm = base + (m4 << 2);
            cnt += (v.x > sk) || (v.x == sk && (gm + 0) < k);
            cnt += (v.y > sk) || (v.y == sk && (gm + 1) < k);
            cnt += (v.z > sk) || (v.z == sk && (gm + 2) < k);
            cnt += (v.w > sk) || (v.w == sk && (gm + 3) < k);
        }
        rankp[mt * NN + k] = cnt;
        return;
    }

    // ---- NMS block (R5 knms verbatim) ----
    const int lane = tid & 63;
    const int wave = tid >> 6;
    const int offs_di[12] = {0,0, 0,0, -1,1, -2,2, -1,-1, 1,1};
    const int offs_dj[12] = {-1,1,-2,2,  0,0,  0,0, -1, 1,-1,1};
    for (int i = tid; i < NN/4; i += 1024)
        ((float4*)s)[i] = ((const float4*)cls)[i];
    __syncthreads();
    // Build H masks + K/D init via ballot. Word w: row w>>1, col base 64*(w&1);
    // lane l <-> col base+l. 16 waves x 12 iters = 192 words.
    for (int it = 0; it < 12; ++it) {
        const int w = wave + (it << 4);
        const int row = w >> 1;
        const int col = ((w & 1) << 6) + lane;
        const bool incell = (col < WW);
        const int c = row * WW + col;
        const float sc = incell ? s[c] : 0.0f;
        const int xi = coord1(col), yi = coord1(row);
        const unsigned long long dinit = __ballot(!incell || !(sc > 0.6f));
        if (lane == 0) { D[w] = dinit; K[w] = 0ULL; }
        #pragma unroll
        for (int e = 0; e < 12; ++e) {
            const int ii = row + offs_di[e], jj = col + offs_dj[e];
            bool hp = false;
            if (incell && ii >= 0 && ii < HH && jj >= 0 && jj < WW) {
                int dx = xi - coord1(jj); dx = dx < 0 ? -dx : dx;
                int dy = yi - coord1(ii); dy = dy < 0 ? -dy : dy;
                if ((21 - dx) * (21 - dy) > 294) {   // exact iou>0.5
                    const int v = ii * WW + jj;
                    const float sv = s[v];
                    hp = (sv > sc) || (sv == sc && v < c);
                }
            }
            const unsigned long long m = __ballot(hp);
            if (lane == 0) Hh[e][w] = m;
        }
    }
    __syncthreads();
    // Monotone fixpoint: thread w<192 owns word w. Stale reads safe (monotone).
    unsigned long long Hr[12];
    const int w = tid;
    int row = 0, h = 0;
    if (w < NW) {
        #pragma unroll
        for (int e = 0; e < 12; ++e) Hr[e] = Hh[e][w];
        row = w >> 1; h = w & 1;
    }
    for (int round = 0; round < 256; ++round) {
        int undet = 0;
        if (w < NW) {
            const unsigned long long Dw = D[w];
            if (~Dw) {
                unsigned long long KA[5], KB[5], DA[5], DB[5];
                #pragma unroll
                for (int q = 0; q < 5; ++q) {
                    const int rr = row + q - 2;
                    const bool ok = (rr >= 0) && (rr < HH);
                    KA[q] = ok ? K[rr*2]   : 0ULL;
                    KB[q] = ok ? K[rr*2+1] : 0ULL;
                    DA[q] = ok ? D[rr*2]   : 0ULL;
                    DB[q] = ok ? D[rr*2+1] : 0ULL;
                }
                unsigned long long supp = 0ULL, alldet = ~0ULL;
                #pragma unroll
                for (int e = 0; e < 12; ++e) {
                    const int q = offs_di[e] + 2;
                    const int dj = offs_dj[e];
                    supp   |=  Hr[e] & shifted(KA[q], KB[q], h, dj);
                    alldet &= ~Hr[e] | shifted(DA[q], DB[q], h, dj);
                }
                const unsigned long long U = ~Dw;
                const unsigned long long newK = K[w] | (U & alldet & ~supp);
                const unsigned long long newD = Dw | (U & (supp | alldet));
                K[w] = newK; D[w] = newD;
                undet = ((~newD) != 0ULL) ? 1 : 0;
            }
        }
        if (__syncthreads_count(undet) == 0) break;
    }
    if (w < NW) kw[w] = K[w];
}

// Epilogue: r = rank[k] is a permutation of [0,9216) — every output row
// written exactly once (non-kept rows -> zeros, no d_out memset needed).
__global__ void kout(const float* __restrict__ score, const float* __restrict__ reg,
                     const int* __restrict__ rankp,
                     const unsigned long long* __restrict__ kw,
                     float* __restrict__ out) {
    const int k = blockIdx.x * 256 + threadIdx.x;
    int r = 0;
    #pragma unroll
    for (int y = 0; y < 9; ++y) r += rankp[y * NN + k];
    const int j = k % WW, i = k / WW;
    const bool kp = ((kw[i * 2 + (j >> 6)] >> (j & 63)) & 1ULL) != 0ULL;
    const float x1 = (float)coord1(j);
    const float y1 = (float)coord1(i);
    const float4 d = ((const float4*)reg)[k];
    float* o = out + (size_t)r * 5;
    o[0] = kp ? (x1 + d.x * 21.0f) : 0.0f;
    o[1] = kp ? (y1 + d.y * 21.0f) : 0.0f;
    o[2] = kp ? (x1 + 20.0f + d.z * 21.0f) : 0.0f;
    o[3] = kp ? (y1 + 20.0f + d.w * 21.0f) : 0.0f;
    o[4] = kp ? score[k] : 0.0f;
}

extern "C" void kernel_launch(void* const* d_in, const int* in_sizes, int n_in,
                              void* d_out, int out_size, void* d_ws, size_t ws_size,
                              hipStream_t stream) {
    const float* cls = (const float*)d_in[0];
    const float* reg = (const float*)d_in[1];
    float* out = (float*)d_out;
    char* ws = (char*)d_ws;
    int* rankp = (int*)(ws);
    unsigned long long* kw = (unsigned long long*)(ws + 331776);

    kA<<<82, 1024, 0, stream>>>(cls, rankp, kw);
    kout<<<36, 256, 0, stream>>>(cls, reg, rankp, kw, out);
}

// Round 10
// 97.635 us; speedup vs baseline: 1.3245x; 1.0025x over previous
//
#include <hip/hip_runtime.h>
#include <stdint.h>

#define HH 96
#define WW 96
#define NN (HH*WW)
#define NW 192   // bitmap words: 96 rows x 2 (128-bit padded rows, cols 96..127 dead)

// ws layout (bytes):
//   [0,      331776)  rankp int32[9][9216]  (rank partial sums)
//   [331776, 333312)  kw    u64[192]        (kept bitmap words)

__device__ __forceinline__ int coord1(int a) { return (10 * a + 1) / 3; }

// Aligned shifted word: result bit b (cell col 64h+b) = src-row bit (64h+b+dj).
__device__ __forceinline__ unsigned long long shifted(unsigned long long A,
                                                      unsigned long long B,
                                                      int h, int dj) {
    const unsigned long long W0 = h ? B : A;
    if (dj == 0) return W0;
    if (dj > 0) {
        const unsigned long long Wr = h ? 0ULL : B;
        return (W0 >> dj) | (Wr << (64 - dj));
    }
    const int d = -dj;
    const unsigned long long Wl = h ? A : 0ULL;
    return (W0 << d) | (Wl >> (64 - d));
}

// One dispatch, disjoint block roles, ZERO cross-block sync (R6/R8 lesson).
// Blocks 0..80: counting-rank partials. Block 81: bit-parallel greedy-NMS
// (== lexicographically-first MIS; exact-integer iou>0.5 per R0 analysis;
// 2nd NMS pass @0.7 provably a no-op). R9 post-mortem: the fixpoint's
// 16-wave __syncthreads_count rounds were ~25us of kA's 43.7; the fixpoint
// is monotone, so waves 3..15 exit after H-build and waves 0..2 free-run
// with volatile LDS (chaotic iteration -> same least fixpoint, no barriers).
__global__ __launch_bounds__(1024, 1) void kA(const float* __restrict__ cls,
                                              int* __restrict__ rankp,
                                              unsigned long long* __restrict__ kw) {
    __shared__ __align__(16) float s[NN];         // 36 KB (rank blocks use 4 KB)
    __shared__ unsigned long long Hh[12][NW];     // 18 KB
    __shared__ unsigned long long K[NW], D[NW];   // 3 KB
    const int tid = threadIdx.x;
    const int bid = blockIdx.x;

    if (bid < 81) {
        // ---- rank partials: pair p=(k-tile, m-tile) of 1024 cells each ----
        const int kt = bid % 9, mt = bid / 9;
        const int base = mt * 1024;
        float4* smf = (float4*)s;
        if (tid < 256) smf[tid] = ((const float4*)(cls + base))[tid];
        __syncthreads();
        const int k = kt * 1024 + tid;
        const float sk = cls[k];
        int cnt = 0;
        #pragma unroll 4
        for (int m4 = 0; m4 < 256; ++m4) {
            const float4 v = smf[m4];
            const int gm = base + (m4 << 2);
            cnt += (v.x > sk) || (v.x == sk && (gm + 0) < k);
            cnt += (v.y > sk) || (v.y == sk && (gm + 1) < k);
            cnt += (v.z > sk) || (v.z == sk && (gm + 2) < k);
            cnt += (v.w > sk) || (v.w == sk && (gm + 3) < k);
        }
        rankp[mt * NN + k] = cnt;
        return;
    }

    // ---- NMS block ----
    const int lane = tid & 63;
    const int wave = tid >> 6;
    const int offs_di[12] = {0,0, 0,0, -1,1, -2,2, -1,-1, 1,1};
    const int offs_dj[12] = {-1,1,-2,2,  0,0,  0,0, -1, 1,-1,1};
    for (int i = tid; i < NN/4; i += 1024)
        ((float4*)s)[i] = ((const float4*)cls)[i];
    __syncthreads();
    // Build H masks + K/D init via ballot. Word w: row w>>1, col base 64*(w&1);
    // lane l <-> col base+l. 16 waves x 12 iters = 192 words.
    for (int it = 0; it < 12; ++it) {
        const int w = wave + (it << 4);
        const int row = w >> 1;
        const int col = ((w & 1) << 6) + lane;
        const bool incell = (col < WW);
        const int c = row * WW + col;
        const float sc = incell ? s[c] : 0.0f;
        const int xi = coord1(col), yi = coord1(row);
        const unsigned long long dinit = __ballot(!incell || !(sc > 0.6f));
        if (lane == 0) { D[w] = dinit; K[w] = 0ULL; }
        #pragma unroll
        for (int e = 0; e < 12; ++e) {
            const int ii = row + offs_di[e], jj = col + offs_dj[e];
            bool hp = false;
            if (incell && ii >= 0 && ii < HH && jj >= 0 && jj < WW) {
                int dx = xi - coord1(jj); dx = dx < 0 ? -dx : dx;
                int dy = yi - coord1(ii); dy = dy < 0 ? -dy : dy;
                if ((21 - dx) * (21 - dy) > 294) {   // exact iou>0.5
                    const int v = ii * WW + jj;
                    const float sv = s[v];
                    hp = (sv > sc) || (sv == sc && v < c);
                }
            }
            const unsigned long long m = __ballot(hp);
            if (lane == 0) Hh[e][w] = m;
        }
    }
    __syncthreads();          // last barrier: all 16 waves present
    if (wave >= 3) return;    // waves 3..15 done; 0..2 free-run (no barriers)

    // Free-running monotone fixpoint: thread w (=tid, 0..191) owns word w.
    // Write order K-then-D, read order D-then-K: LDS applies per-wave ops in
    // order and volatile preserves program order, so D=1 observed => that
    // neighbor's K is current (no false "determined-not-kept").
    volatile unsigned long long* vK = K;
    volatile unsigned long long* vD = D;
    const int w = tid;
    const int row = w >> 1, h = w & 1;
    unsigned long long Hr[12];
    #pragma unroll
    for (int e = 0; e < 12; ++e) Hr[e] = Hh[e][w];
    unsigned long long myK = K[w], myD = D[w];    // own words: only this thread writes
    for (int iter = 0; iter < 4096; ++iter) {
        if (!~myD) break;                          // fully determined: final
        unsigned long long DA[5], DB[5], KA[5], KB[5];
        #pragma unroll
        for (int q = 0; q < 5; ++q) {              // D reads FIRST
            const int rr = row + q - 2;
            const bool ok = (rr >= 0) && (rr < HH);
            DA[q] = ok ? vD[rr*2]   : 0ULL;
            DB[q] = ok ? vD[rr*2+1] : 0ULL;        // out-of-grid: H=0 there anyway
        }
        #pragma unroll
        for (int q = 0; q < 5; ++q) {              // K reads AFTER D
            const int rr = row + q - 2;
            const bool ok = (rr >= 0) && (rr < HH);
            KA[q] = ok ? vK[rr*2]   : 0ULL;
            KB[q] = ok ? vK[rr*2+1] : 0ULL;
        }
        unsigned long long supp = 0ULL, alldet = ~0ULL;
        #pragma unroll
        for (int e = 0; e < 12; ++e) {
            const int q = offs_di[e] + 2;
            const int dj = offs_dj[e];
            supp   |=  Hr[e] & shifted(KA[q], KB[q], h, dj);
            alldet &= ~Hr[e] | shifted(DA[q], DB[q], h, dj);
        }
        const unsigned long long U = ~myD;
        myK = myK | (U & alldet & ~supp);
        myD = myD | (U & (supp | alldet));
        vK[w] = myK;                               // K write BEFORE D write
        vD[w] = myD;
    }
    kw[w] = myK;   // own word final; no cross-wave read needed
}

// Epilogue: r = rank[k] is a permutation of [0,9216) — every output row
// written exactly once (non-kept rows -> zeros, no d_out memset needed).
__global__ void kout(const float* __restrict__ score, const float* __restrict__ reg,
                     const int* __restrict__ rankp,
                     const unsigned long long* __restrict__ kw,
                     float* __restrict__ out) {
    const int k = blockIdx.x * 256 + threadIdx.x;
    int r = 0;
    #pragma unroll
    for (int y = 0; y < 9; ++y) r += rankp[y * NN + k];
    const int j = k % WW, i = k / WW;
    const bool kp = ((kw[i * 2 + (j >> 6)] >> (j & 63)) & 1ULL) != 0ULL;
    const float x1 = (float)coord1(j);
    const float y1 = (float)coord1(i);
    const float4 d = ((const float4*)reg)[k];
    float* o = out + (size_t)r * 5;
    o[0] = kp ? (x1 + d.x * 21.0f) : 0.0f;
    o[1] = kp ? (y1 + d.y * 21.0f) : 0.0f;
    o[2] = kp ? (x1 + 20.0f + d.z * 21.0f) : 0.0f;
    o[3] = kp ? (y1 + 20.0f + d.w * 21.0f) : 0.0f;
    o[4] = kp ? score[k] : 0.0f;
}

extern "C" void kernel_launch(void* const* d_in, const int* in_sizes, int n_in,
                              void* d_out, int out_size, void* d_ws, size_t ws_size,
                              hipStream_t stream) {
    const float* cls = (const float*)d_in[0];
    const float* reg = (const float*)d_in[1];
    float* out = (float*)d_out;
    char* ws = (char*)d_ws;
    int* rankp = (int*)(ws);
    unsigned long long* kw = (unsigned long long*)(ws + 331776);

    kA<<<82, 1024, 0, stream>>>(cls, rankp, kw);
    kout<<<36, 256, 0, stream>>>(cls, reg, rankp, kw, out);
}